// Round 2
// baseline (3088.716 us; speedup 1.0000x reference)
//
#include <hip/hip_runtime.h>
#include <hip/hip_bf16.h>

typedef __bf16 bf16;
typedef __bf16 bf16x8 __attribute__((ext_vector_type(8)));
typedef float f32x4 __attribute__((ext_vector_type(4)));

__device__ __forceinline__ bf16 f2bf(float f) {
    unsigned u = __builtin_bit_cast(unsigned, f);
    u = (u + 0x7FFFu + ((u >> 16) & 1u)) >> 16;
    unsigned short s = (unsigned short)u;
    return __builtin_bit_cast(bf16, s);
}

// load 16 contiguous elements as bf16 (converting if fp32)
__device__ __forceinline__ void load16(const float* p, bf16* o) {
    #pragma unroll
    for (int i = 0; i < 4; ++i) {
        f32x4 f = *(const f32x4*)(p + i * 4);
        #pragma unroll
        for (int j = 0; j < 4; ++j) o[i * 4 + j] = f2bf(f[j]);
    }
}
__device__ __forceinline__ void load16(const bf16* p, bf16* o) {
    *(bf16x8*)o       = *(const bf16x8*)p;
    *(bf16x8*)(o + 8) = *(const bf16x8*)(p + 8);
}

__device__ __forceinline__ void store_c(float* p, float v) { *p = v; }
__device__ __forceinline__ void store_c(bf16*  p, float v) { *p = f2bf(v); }

#define BM 128
#define BN 128
#define BK 32
#define PAD 8   // LDS row stride 40 bf16 = 80 B (16B-aligned, bank-spread)

// C[M,N] = A[M,K] @ B[K,N], row-major, bf16 MFMA with fp32 accumulate.
template <typename TA, typename TB, typename TC>
__global__ __launch_bounds__(256) void gemm_t(
    const TA* __restrict__ A, const TB* __restrict__ B, TC* __restrict__ C,
    int M, int N, int K)
{
    __shared__ alignas(16) bf16 As[BM][BK + PAD];
    __shared__ alignas(16) bf16 Bs[BN][BK + PAD];   // stored transposed: Bs[n][k]

    const int tid  = threadIdx.x;
    const int wv   = tid >> 6;
    const int lane = tid & 63;
    const int lr   = lane & 15;   // fragment row/col
    const int kb   = lane >> 4;   // k-block 0..3
    const int wr   = wv >> 1, wc = wv & 1;
    const int brow = blockIdx.y * BM;
    const int bcol = blockIdx.x * BN;

    f32x4 acc[4][4] = {};

    const int arow = tid >> 1,  acol = (tid & 1) * 16;
    const int bk   = tid >> 3,  bn0  = (tid & 7) * 16;

    for (int k0 = 0; k0 < K; k0 += BK) {
        alignas(16) bf16 av[16], bv[16];
        load16(A + (size_t)(brow + arow) * K + k0 + acol, av);
        load16(B + (size_t)(k0 + bk)   * N + bcol + bn0, bv);

        __syncthreads();   // previous tile fully consumed
        *(bf16x8*)&As[arow][acol]     = *(bf16x8*)av;
        *(bf16x8*)&As[arow][acol + 8] = *(bf16x8*)(av + 8);
        #pragma unroll
        for (int e = 0; e < 16; ++e) Bs[bn0 + e][bk] = bv[e];
        __syncthreads();

        bf16x8 af[4], bfr[4];
        #pragma unroll
        for (int m = 0; m < 4; ++m) af[m]  = *(const bf16x8*)&As[wr*64 + m*16 + lr][kb*8];
        #pragma unroll
        for (int n = 0; n < 4; ++n) bfr[n] = *(const bf16x8*)&Bs[wc*64 + n*16 + lr][kb*8];
        #pragma unroll
        for (int m = 0; m < 4; ++m)
            #pragma unroll
            for (int n = 0; n < 4; ++n)
                acc[m][n] = __builtin_amdgcn_mfma_f32_16x16x32_bf16(af[m], bfr[n], acc[m][n], 0, 0, 0);
    }

    #pragma unroll
    for (int m = 0; m < 4; ++m)
        #pragma unroll
        for (int n = 0; n < 4; ++n)
            #pragma unroll
            for (int r = 0; r < 4; ++r) {
                int row = brow + wr*64 + m*16 + kb*4 + r;   // row=(lane>>4)*4+reg (verified layout)
                int col = bcol + wc*64 + n*16 + lr;         // col=lane&15
                store_c(&C[(size_t)row * N + col], acc[m][n][r]);
            }
}

// Flash-style attention, VALU (fp32) math. qkv layout: [(b*2048+s)*3072 + {0|1024|2048} + h*64 + d]
// Block: 256 threads = 4 waves; each wave owns 4 q-rows; block = one (b,h) x 16 q-rows.
__global__ __launch_bounds__(256) void attn_fwd(
    const bf16* __restrict__ qkv, bf16* __restrict__ attn_out)
{
    constexpr int NSEQ = 2048, DMODEL = 1024, QKV_LD = 3072, DKH = 64, TK = 128;
    __shared__ alignas(16) bf16 Qs[16][DKH];       // 2 KB
    __shared__ alignas(16) bf16 Kt[DKH][TK];       // transposed: Kt[d][j], 16 KB
    __shared__ alignas(16) bf16 Vs[TK][DKH + 8];   // stride 72 bf16 = 144 B
    __shared__ float Ps[4][TK];                    // per-wave softmax weights

    const int tid = threadIdx.x;
    const int wv = tid >> 6, lane = tid & 63;
    const int q0 = blockIdx.x * 16;
    const int bh = blockIdx.y;
    const int b = bh >> 4, h = bh & 15;

    const bf16* qbase = qkv + (size_t)(b * NSEQ) * QKV_LD + h * DKH;
    const bf16* kbase = qbase + DMODEL;
    const bf16* vbase = qbase + 2 * DMODEL;

    if (tid < 128) {
        int r = tid >> 3, c = (tid & 7) * 8;
        *(bf16x8*)&Qs[r][c] = *(const bf16x8*)(qbase + (size_t)(q0 + r) * QKV_LD + c);
    }

    float m_r[4], l_r[4], o_r[4];
    #pragma unroll
    for (int r = 0; r < 4; ++r) { m_r[r] = -INFINITY; l_r[r] = 0.f; o_r[r] = 0.f; }

    const int sr = tid >> 1;         // staging row 0..127
    const int sc = (tid & 1) * 32;   // col half

    for (int kt = 0; kt < NSEQ / TK; ++kt) {
        const int j0 = kt * TK;
        bf16x8 kv[4], vvv[4];
        #pragma unroll
        for (int e = 0; e < 4; ++e) {
            kv[e]  = *(const bf16x8*)(kbase + (size_t)(j0 + sr) * QKV_LD + sc + e*8);
            vvv[e] = *(const bf16x8*)(vbase + (size_t)(j0 + sr) * QKV_LD + sc + e*8);
        }
        __syncthreads();   // previous tile consumed (also orders the Q-tile writes)
        #pragma unroll
        for (int e = 0; e < 4; ++e) {
            #pragma unroll
            for (int c = 0; c < 8; ++c) Kt[sc + e*8 + c][sr] = kv[e][c];
            *(bf16x8*)&Vs[sr][sc + e*8] = vvv[e];
        }
        __syncthreads();

        #pragma unroll
        for (int r = 0; r < 4; ++r) {
            const int qr = wv * 4 + r;
            float s0 = 0.f, s1 = 0.f;
            #pragma unroll
            for (int d = 0; d < DKH; ++d) {
                float qd = (float)Qs[qr][d];            // broadcast read
                s0 += qd * (float)Kt[d][lane];          // consecutive lanes -> conflict-free
                s1 += qd * (float)Kt[d][lane + 64];
            }
            s0 *= 0.125f; s1 *= 0.125f;
            float tm = fmaxf(s0, s1);
            #pragma unroll
            for (int off = 32; off; off >>= 1) tm = fmaxf(tm, __shfl_xor(tm, off));
            float m_new = fmaxf(m_r[r], tm);
            float corr = __expf(m_r[r] - m_new);        // first tile: exp(-inf)=0
            float p0 = __expf(s0 - m_new), p1 = __expf(s1 - m_new);
            float ps = p0 + p1;
            #pragma unroll
            for (int off = 32; off; off >>= 1) ps += __shfl_xor(ps, off);
            l_r[r] = l_r[r] * corr + ps;
            m_r[r] = m_new;
            Ps[wv][lane] = p0; Ps[wv][lane + 64] = p1;  // per-wave region, wave-lockstep safe
            float o = o_r[r] * corr;
            #pragma unroll 8
            for (int j = 0; j < TK; ++j)
                o += Ps[wv][j] * (float)Vs[j][lane];    // Ps broadcast; Vs consecutive lanes
            o_r[r] = o;
        }
    }

    #pragma unroll
    for (int r = 0; r < 4; ++r) {
        const int qr = wv * 4 + r;
        attn_out[(size_t)(b * NSEQ + q0 + qr) * DMODEL + h * DKH + lane] = f2bf(o_r[r] / l_r[r]);
    }
}

extern "C" void kernel_launch(void* const* d_in, const int* in_sizes, int n_in,
                              void* d_out, int out_size, void* d_ws, size_t ws_size,
                              hipStream_t stream) {
    const float* x     = (const float*)d_in[0];   // [4,2048,1024] fp32
    const float* w_qkv = (const float*)d_in[1];   // [1024,3072]  fp32
    const float* w_out = (const float*)d_in[2];   // [1024,1024]  fp32
    float* out = (float*)d_out;                   // [4,2048,1024] fp32
    bf16* qkv  = (bf16*)d_ws;                     // [8192,3072] bf16 = 50.3 MB
    bf16* attn = qkv + (size_t)8192 * 3072;       // [8192,1024] bf16 = 16.8 MB

    gemm_t<float, float, bf16><<<dim3(3072/128, 8192/128), 256, 0, stream>>>(x, w_qkv, qkv, 8192, 3072, 1024);
    attn_fwd<<<dim3(2048/16, 64), 256, 0, stream>>>(qkv, attn);
    gemm_t<bf16, float, float><<<dim3(1024/128, 8192/128), 256, 0, stream>>>(attn, w_out, out, 8192, 1024, 1024);
}

// Round 3
// 458.201 us; speedup vs baseline: 6.7410x; 6.7410x over previous
//
#include <hip/hip_runtime.h>
#include <hip/hip_bf16.h>

typedef __bf16 bf16;
typedef __bf16 bf16x8 __attribute__((ext_vector_type(8)));
typedef float f32x4 __attribute__((ext_vector_type(4)));

__device__ __forceinline__ bf16 f2bf(float f) {
    unsigned u = __builtin_bit_cast(unsigned, f);
    u = (u + 0x7FFFu + ((u >> 16) & 1u)) >> 16;
    unsigned short s = (unsigned short)u;
    return __builtin_bit_cast(bf16, s);
}

// load 16 contiguous elements as bf16 (converting if fp32)
__device__ __forceinline__ void load16(const float* p, bf16* o) {
    #pragma unroll
    for (int i = 0; i < 4; ++i) {
        f32x4 f = *(const f32x4*)(p + i * 4);
        #pragma unroll
        for (int j = 0; j < 4; ++j) o[i * 4 + j] = f2bf(f[j]);
    }
}
__device__ __forceinline__ void load16(const bf16* p, bf16* o) {
    *(bf16x8*)o       = *(const bf16x8*)p;
    *(bf16x8*)(o + 8) = *(const bf16x8*)(p + 8);
}

__device__ __forceinline__ void store_c(float* p, float v) { *p = v; }
__device__ __forceinline__ void store_c(bf16*  p, float v) { *p = f2bf(v); }

#define BM 128
#define BN 128
#define BK 32
#define PAD 8   // LDS row stride 40 bf16 = 80 B (16B-aligned, bank-spread)

// C[M,N] = A[M,K] @ B[K,N], row-major, bf16 MFMA with fp32 accumulate.
template <typename TA, typename TB, typename TC>
__global__ __launch_bounds__(256) void gemm_t(
    const TA* __restrict__ A, const TB* __restrict__ B, TC* __restrict__ C,
    int M, int N, int K)
{
    __shared__ alignas(16) bf16 As[BM][BK + PAD];
    __shared__ alignas(16) bf16 Bs[BN][BK + PAD];   // stored transposed: Bs[n][k]

    const int tid  = threadIdx.x;
    const int wv   = tid >> 6;
    const int lane = tid & 63;
    const int lr   = lane & 15;   // fragment row/col
    const int kb   = lane >> 4;   // k-block 0..3
    const int wr   = wv >> 1, wc = wv & 1;
    const int brow = blockIdx.y * BM;
    const int bcol = blockIdx.x * BN;

    f32x4 acc[4][4] = {};

    const int arow = tid >> 1,  acol = (tid & 1) * 16;
    const int bk   = tid >> 3,  bn0  = (tid & 7) * 16;

    for (int k0 = 0; k0 < K; k0 += BK) {
        alignas(16) bf16 av[16], bv[16];
        load16(A + (size_t)(brow + arow) * K + k0 + acol, av);
        load16(B + (size_t)(k0 + bk)   * N + bcol + bn0, bv);

        __syncthreads();   // previous tile fully consumed
        *(bf16x8*)&As[arow][acol]     = *(bf16x8*)av;
        *(bf16x8*)&As[arow][acol + 8] = *(bf16x8*)(av + 8);
        #pragma unroll
        for (int e = 0; e < 16; ++e) Bs[bn0 + e][bk] = bv[e];
        __syncthreads();

        bf16x8 af[4], bfr[4];
        #pragma unroll
        for (int m = 0; m < 4; ++m) af[m]  = *(const bf16x8*)&As[wr*64 + m*16 + lr][kb*8];
        #pragma unroll
        for (int n = 0; n < 4; ++n) bfr[n] = *(const bf16x8*)&Bs[wc*64 + n*16 + lr][kb*8];
        #pragma unroll
        for (int m = 0; m < 4; ++m)
            #pragma unroll
            for (int n = 0; n < 4; ++n)
                acc[m][n] = __builtin_amdgcn_mfma_f32_16x16x32_bf16(af[m], bfr[n], acc[m][n], 0, 0, 0);
    }

    #pragma unroll
    for (int m = 0; m < 4; ++m)
        #pragma unroll
        for (int n = 0; n < 4; ++n)
            #pragma unroll
            for (int r = 0; r < 4; ++r) {
                int row = brow + wr*64 + m*16 + kb*4 + r;   // row=(lane>>4)*4+reg (verified layout)
                int col = bcol + wc*64 + n*16 + lr;         // col=lane&15
                store_c(&C[(size_t)row * N + col], acc[m][n][r]);
            }
}

// MFMA flash attention. qkv layout: [(b*2048+s)*3072 + {0|1024|2048} + h*64 + d]
// Block = 256 threads (4 waves) = one (b,h) x 64 q-rows; each wave owns 16 q-rows.
// KV-tile = 64. QK^T and PV via mfma_f32_16x16x32_bf16, fp32 online softmax.
__global__ __launch_bounds__(256) void attn_mfma(
    const bf16* __restrict__ qkv, bf16* __restrict__ attn_out)
{
    constexpr int NSEQ = 2048, DM = 1024, LD = 3072, DKH = 64, KVB = 64, QB = 64;
    __shared__ alignas(16) bf16 Ks[KVB][DKH + 8];      // [k][d] row-major, stride 144 B
    __shared__ alignas(16) bf16 Vt[DKH][KVB + 8];      // [d][k] transposed
    __shared__ alignas(16) bf16 Pl[4][16][KVB + 8];    // per-wave P [q][k]

    const int tid = threadIdx.x;
    const int wv = tid >> 6, lane = tid & 63;
    const int lr = lane & 15;     // A/B-frag row; C-frag col
    const int kb = lane >> 4;     // A/B-frag k-block; C-frag row-group
    const int q0 = blockIdx.x * QB;
    const int bh = blockIdx.y;
    const int b = bh >> 4, h = bh & 15;

    const bf16* qbase = qkv + (size_t)(b * NSEQ) * LD + h * DKH;
    const bf16* kbase = qbase + DM;
    const bf16* vbase = qbase + 2 * DM;

    // Q fragments in registers, pre-scaled by 1/sqrt(64)=0.125 (exact in bf16)
    bf16x8 qf[2];
    #pragma unroll
    for (int ks = 0; ks < 2; ++ks) {
        bf16x8 t = *(const bf16x8*)(qbase + (size_t)(q0 + wv * 16 + lr) * LD + ks * 32 + kb * 8);
        #pragma unroll
        for (int e = 0; e < 8; ++e) t[e] = f2bf((float)t[e] * 0.125f);
        qf[ks] = t;
    }

    f32x4 o[4] = {};                       // [d-tile]; o[dt][r], q=kb*4+r, d=dt*16+lr
    float m_r[4], l_r[4];
    #pragma unroll
    for (int r = 0; r < 4; ++r) { m_r[r] = -INFINITY; l_r[r] = 0.f; }

    const int srow = tid >> 2;             // staging row 0..63
    const int scg  = (tid & 3) * 16;       // staging col group

    for (int kt = 0; kt < NSEQ / KVB; ++kt) {
        const int j0 = kt * KVB;
        bf16x8 kr0 = *(const bf16x8*)(kbase + (size_t)(j0 + srow) * LD + scg);
        bf16x8 kr1 = *(const bf16x8*)(kbase + (size_t)(j0 + srow) * LD + scg + 8);
        bf16x8 vr0 = *(const bf16x8*)(vbase + (size_t)(j0 + srow) * LD + scg);
        bf16x8 vr1 = *(const bf16x8*)(vbase + (size_t)(j0 + srow) * LD + scg + 8);

        __syncthreads();                   // previous tile fully consumed
        *(bf16x8*)&Ks[srow][scg]     = kr0;
        *(bf16x8*)&Ks[srow][scg + 8] = kr1;
        #pragma unroll
        for (int e = 0; e < 8; ++e) {
            Vt[scg + e][srow]     = vr0[e];
            Vt[scg + 8 + e][srow] = vr1[e];
        }
        __syncthreads();

        // --- QK^T: S[16q x 64k], 4 n-tiles x 2 k-steps ---
        f32x4 s[4];
        #pragma unroll
        for (int nt = 0; nt < 4; ++nt) {
            s[nt] = (f32x4){0.f, 0.f, 0.f, 0.f};
            #pragma unroll
            for (int ks = 0; ks < 2; ++ks) {
                bf16x8 kf = *(const bf16x8*)&Ks[nt * 16 + lr][ks * 32 + kb * 8];
                s[nt] = __builtin_amdgcn_mfma_f32_16x16x32_bf16(qf[ks], kf, s[nt], 0, 0, 0);
            }
        }

        // --- online softmax; per-lane stats for q = kb*4 + r ---
        float corr[4];
        #pragma unroll
        for (int r = 0; r < 4; ++r) {
            float tm = fmaxf(fmaxf(s[0][r], s[1][r]), fmaxf(s[2][r], s[3][r]));
            #pragma unroll
            for (int off = 8; off; off >>= 1) tm = fmaxf(tm, __shfl_xor(tm, off));
            float mn = fmaxf(m_r[r], tm);
            corr[r] = __expf(m_r[r] - mn);
            m_r[r] = mn;
        }
        float ps[4] = {0.f, 0.f, 0.f, 0.f};
        #pragma unroll
        for (int nt = 0; nt < 4; ++nt)
            #pragma unroll
            for (int r = 0; r < 4; ++r) {
                float p = __expf(s[nt][r] - m_r[r]);
                ps[r] += p;
                Pl[wv][kb * 4 + r][nt * 16 + lr] = f2bf(p);
            }
        #pragma unroll
        for (int r = 0; r < 4; ++r) {
            float t = ps[r];
            #pragma unroll
            for (int off = 8; off; off >>= 1) t += __shfl_xor(t, off);
            l_r[r] = l_r[r] * corr[r] + t;
        }
        #pragma unroll
        for (int dt = 0; dt < 4; ++dt)
            #pragma unroll
            for (int r = 0; r < 4; ++r) o[dt][r] *= corr[r];

        // --- PV: O[16q x 64d] += P @ V  (P from per-wave LDS, V^T rows) ---
        bf16x8 pf[2];
        #pragma unroll
        for (int ks = 0; ks < 2; ++ks) pf[ks] = *(const bf16x8*)&Pl[wv][lr][ks * 32 + kb * 8];
        #pragma unroll
        for (int dt = 0; dt < 4; ++dt)
            #pragma unroll
            for (int ks = 0; ks < 2; ++ks) {
                bf16x8 vf = *(const bf16x8*)&Vt[dt * 16 + lr][ks * 32 + kb * 8];
                o[dt] = __builtin_amdgcn_mfma_f32_16x16x32_bf16(pf[ks], vf, o[dt], 0, 0, 0);
            }
    }

    #pragma unroll
    for (int r = 0; r < 4; ++r) {
        const float inv = 1.f / l_r[r];
        const int grow = q0 + wv * 16 + kb * 4 + r;
        #pragma unroll
        for (int dt = 0; dt < 4; ++dt)
            attn_out[(size_t)(b * NSEQ + grow) * DM + h * DKH + dt * 16 + lr] = f2bf(o[dt][r] * inv);
    }
}

extern "C" void kernel_launch(void* const* d_in, const int* in_sizes, int n_in,
                              void* d_out, int out_size, void* d_ws, size_t ws_size,
                              hipStream_t stream) {
    const float* x     = (const float*)d_in[0];   // [4,2048,1024] fp32
    const float* w_qkv = (const float*)d_in[1];   // [1024,3072]  fp32
    const float* w_out = (const float*)d_in[2];   // [1024,1024]  fp32
    float* out = (float*)d_out;                   // [4,2048,1024] fp32
    bf16* qkv  = (bf16*)d_ws;                     // [8192,3072] bf16 = 50.3 MB
    bf16* attn = qkv + (size_t)8192 * 3072;       // [8192,1024] bf16 = 16.8 MB

    gemm_t<float, float, bf16><<<dim3(3072/128, 8192/128), 256, 0, stream>>>(x, w_qkv, qkv, 8192, 3072, 1024);
    attn_mfma<<<dim3(2048/64, 64), 256, 0, stream>>>(qkv, attn);
    gemm_t<bf16, float, float><<<dim3(1024/128, 8192/128), 256, 0, stream>>>(attn, w_out, out, 8192, 1024, 1024);
}

// Round 4
// 319.716 us; speedup vs baseline: 9.6608x; 1.4331x over previous
//
#include <hip/hip_runtime.h>
#include <hip/hip_bf16.h>

typedef __bf16 bf16;
typedef __bf16 bf16x8 __attribute__((ext_vector_type(8)));
typedef float f32x4 __attribute__((ext_vector_type(4)));
typedef float f32x16 __attribute__((ext_vector_type(16)));
typedef short s16x4 __attribute__((ext_vector_type(4)));

__device__ __forceinline__ bf16 f2bf(float f) {
    unsigned u = __builtin_bit_cast(unsigned, f);
    u = (u + 0x7FFFu + ((u >> 16) & 1u)) >> 16;
    unsigned short s = (unsigned short)u;
    return __builtin_bit_cast(bf16, s);
}

// load 16 contiguous elements as bf16 (converting if fp32)
__device__ __forceinline__ void load16(const float* p, bf16* o) {
    #pragma unroll
    for (int i = 0; i < 4; ++i) {
        f32x4 f = *(const f32x4*)(p + i * 4);
        #pragma unroll
        for (int j = 0; j < 4; ++j) o[i * 4 + j] = f2bf(f[j]);
    }
}
__device__ __forceinline__ void load16(const bf16* p, bf16* o) {
    *(bf16x8*)o       = *(const bf16x8*)p;
    *(bf16x8*)(o + 8) = *(const bf16x8*)(p + 8);
}

__device__ __forceinline__ void store_c(float* p, float v) { *p = v; }
__device__ __forceinline__ void store_c(bf16*  p, float v) { *p = f2bf(v); }

__device__ __forceinline__ unsigned cvt_pk_bf16(float lo, float hi) {
    unsigned r;
    asm("v_cvt_pk_bf16_f32 %0, %1, %2" : "=v"(r) : "v"(lo), "v"(hi));
    return r;
}
// v_permlane32_swap_b32: a.hi32lanes <-> b.lo32lanes =>
//  a' = lane<32 ? a[l] : b[l-32];  b' = lane<32 ? a[l+32] : b[l]
__device__ __forceinline__ void permlane32_swap(unsigned &a, unsigned &b) {
    asm("v_permlane32_swap_b32 %0, %1" : "+v"(a), "+v"(b));
}
// LDS transpose read: 16-lane group collectively loads a [4][16] bf16 subtile
// (lane supplies base + (lane&15)*8); lane gets column (lane&15), elems j=rows 0..3.
__device__ __forceinline__ s16x4 ds_tr16(unsigned addr) {
    s16x4 d;
    asm volatile("ds_read_b64_tr_b16 %0, %1" : "=v"(d) : "v"(addr));
    return d;
}

#define BM 128
#define BN 128
#define BK 32
#define PAD 8   // LDS row stride 40 bf16 = 80 B

// C[M,N] = A[M,K] @ B[K,N], row-major, bf16 MFMA with fp32 accumulate.
template <typename TA, typename TB, typename TC>
__global__ __launch_bounds__(256) void gemm_t(
    const TA* __restrict__ A, const TB* __restrict__ B, TC* __restrict__ C,
    int M, int N, int K)
{
    __shared__ alignas(16) bf16 As[BM][BK + PAD];
    __shared__ alignas(16) bf16 Bs[BN][BK + PAD];   // stored transposed: Bs[n][k]

    const int tid  = threadIdx.x;
    const int wv   = tid >> 6;
    const int lane = tid & 63;
    const int lr   = lane & 15;
    const int kb   = lane >> 4;
    const int wr   = wv >> 1, wc = wv & 1;
    const int brow = blockIdx.y * BM;
    const int bcol = blockIdx.x * BN;

    f32x4 acc[4][4] = {};

    const int arow = tid >> 1,  acol = (tid & 1) * 16;
    const int bk   = tid >> 3,  bn0  = (tid & 7) * 16;

    for (int k0 = 0; k0 < K; k0 += BK) {
        alignas(16) bf16 av[16], bv[16];
        load16(A + (size_t)(brow + arow) * K + k0 + acol, av);
        load16(B + (size_t)(k0 + bk)   * N + bcol + bn0, bv);

        __syncthreads();
        *(bf16x8*)&As[arow][acol]     = *(bf16x8*)av;
        *(bf16x8*)&As[arow][acol + 8] = *(bf16x8*)(av + 8);
        #pragma unroll
        for (int e = 0; e < 16; ++e) Bs[bn0 + e][bk] = bv[e];
        __syncthreads();

        bf16x8 af[4], bfr[4];
        #pragma unroll
        for (int m = 0; m < 4; ++m) af[m]  = *(const bf16x8*)&As[wr*64 + m*16 + lr][kb*8];
        #pragma unroll
        for (int n = 0; n < 4; ++n) bfr[n] = *(const bf16x8*)&Bs[wc*64 + n*16 + lr][kb*8];
        #pragma unroll
        for (int m = 0; m < 4; ++m)
            #pragma unroll
            for (int n = 0; n < 4; ++n)
                acc[m][n] = __builtin_amdgcn_mfma_f32_16x16x32_bf16(af[m], bfr[n], acc[m][n], 0, 0, 0);
    }

    #pragma unroll
    for (int m = 0; m < 4; ++m)
        #pragma unroll
        for (int n = 0; n < 4; ++n)
            #pragma unroll
            for (int r = 0; r < 4; ++r) {
                int row = brow + wr*64 + m*16 + kb*4 + r;
                int col = bcol + wc*64 + n*16 + lr;
                store_c(&C[(size_t)row * N + col], acc[m][n][r]);
            }
}

// ---------------------------------------------------------------------------
// MFMA-32x32 flash attention, swapped-operand structure (m214-style).
// qkv layout: [(b*2048+s)*3072 + {0|1024|2048} + h*64 + d]
// Block = 256 thr (4 waves); wave owns 32 q-rows; block = one (b,h) x 128 q.
// KV tile = 64. S^T = mfma(K,Q): col=q=lane&31, row=kv=(r&3)+8*(r>>2)+4*(l>>5).
// P->bf16 in-register (cvt_pk + permlane32_swap). O^T = mfma(V^T, P^T): col=q,
// so m/l/corr stay lane-local. V read via ds_read_b64_tr_b16 from subtiled LDS.
// ---------------------------------------------------------------------------
__global__ __launch_bounds__(256) void attn_mfma32(
    const bf16* __restrict__ qkv, bf16* __restrict__ attn_out)
{
    constexpr int NSEQ = 2048, DM = 1024, LD = 3072, KVB = 64, QB = 128;
    __shared__ alignas(16) char smem[18432];
    bf16 (*Ks)[72] = (bf16 (*)[72])smem;      // [64 kv][72] row-major K (pad->9 x16B units)
    bf16 *Vs       = (bf16*)(smem + 9216);    // [16 kq][4 cb][4][16] subtiled V (8 KB)
    bf16 (*Os)[72] = (bf16 (*)[72])smem;      // [128 q][72] epilogue overlay

    const int tid = threadIdx.x;
    const int wv = tid >> 6, lane = tid & 63;
    const int l31 = lane & 31;          // q column (and K-row within kv-tile)
    const int hi_ = lane >> 5;          // K-dim half of fragments
    const int g16 = (lane >> 4) & 1;    // 16-col block within tr-read group pair
    const int l16 = lane & 15;
    const int q0 = blockIdx.x * QB;
    const int bh = blockIdx.y;
    const int b = bh >> 4, h = bh & 15;

    const bf16* qbase = qkv + (size_t)(b * NSEQ) * LD + h * 64;
    const bf16* kbase = qbase + DM;
    const bf16* vbase = qbase + 2 * DM;

    // Q fragments (B-operand of swapped QK^T): qf[ds][e] = 0.125*Q[q][ds*16+hi_*8+e]
    bf16x8 qf[4];
    {
        const bf16* qp = qbase + (size_t)(q0 + wv * 32 + l31) * LD + hi_ * 8;
        #pragma unroll
        for (int ds = 0; ds < 4; ++ds) {
            bf16x8 t = *(const bf16x8*)(qp + ds * 16);
            #pragma unroll
            for (int e = 0; e < 8; ++e) t[e] = f2bf((float)t[e] * 0.125f);
            qf[ds] = t;
        }
    }

    f32x16 o0 = {}, o1 = {};            // O^T: rows d (=dt*32+(r&3)+8*(r>>2)+4*hi_), col q
    float mrow = -INFINITY, lsum = 0.f;

    const int krow = tid >> 2, kcol = (tid & 3) * 16;
    const unsigned vb = (unsigned)(uintptr_t)Vs;

    for (int kt = 0; kt < NSEQ / KVB; ++kt) {
        const int j0 = kt * KVB;
        // global prefetch to regs
        bf16x8 kr0 = *(const bf16x8*)(kbase + (size_t)(j0 + krow) * LD + kcol);
        bf16x8 kr1 = *(const bf16x8*)(kbase + (size_t)(j0 + krow) * LD + kcol + 8);
        bf16x8 vr[2];
        #pragma unroll
        for (int w = 0; w < 2; ++w) {
            int L = w * 2048 + tid * 8;                 // linear elem index in Vs
            int kq = L >> 8, cb = (L >> 6) & 3, rr = (L >> 4) & 3, c0 = L & 15;
            vr[w] = *(const bf16x8*)(vbase + (size_t)(j0 + kq * 4 + rr) * LD + cb * 16 + c0);
        }
        __syncthreads();                               // prev tile fully consumed
        *(bf16x8*)&Ks[krow][kcol]       = kr0;
        *(bf16x8*)&Ks[krow][kcol + 8]   = kr1;
        *(bf16x8*)(Vs + tid * 8)        = vr[0];       // linear, conflict-free
        *(bf16x8*)(Vs + 2048 + tid * 8) = vr[1];
        __syncthreads();

        // --- QK^T swapped: sT[kvt] rows kv, col q ---
        f32x16 sT0 = {}, sT1 = {};
        #pragma unroll
        for (int ds = 0; ds < 4; ++ds) {
            bf16x8 kf = *(const bf16x8*)&Ks[l31][ds * 16 + hi_ * 8];
            sT0 = __builtin_amdgcn_mfma_f32_32x32x16_bf16(kf, qf[ds], sT0, 0, 0, 0);
        }
        #pragma unroll
        for (int ds = 0; ds < 4; ++ds) {
            bf16x8 kf = *(const bf16x8*)&Ks[32 + l31][ds * 16 + hi_ * 8];
            sT1 = __builtin_amdgcn_mfma_f32_32x32x16_bf16(kf, qf[ds], sT1, 0, 0, 0);
        }

        // --- online softmax (stats lane-local: one q per lane) ---
        float pm = sT0[0];
        #pragma unroll
        for (int r = 1; r < 16; ++r) pm = fmaxf(pm, sT0[r]);
        #pragma unroll
        for (int r = 0; r < 16; ++r) pm = fmaxf(pm, sT1[r]);
        pm = fmaxf(pm, __shfl_xor(pm, 32));
        const float mn = fmaxf(mrow, pm);
        const float corr = __expf(mrow - mn);
        mrow = mn;
        float ps = 0.f;
        #pragma unroll
        for (int r = 0; r < 16; ++r) { sT0[r] = __expf(sT0[r] - mn); ps += sT0[r]; }
        #pragma unroll
        for (int r = 0; r < 16; ++r) { sT1[r] = __expf(sT1[r] - mn); ps += sT1[r]; }
        ps += __shfl_xor(ps, 32);
        lsum = lsum * corr + ps;
        #pragma unroll
        for (int r = 0; r < 16; ++r) { o0[r] *= corr; o1[r] *= corr; }

        // --- pack P to bf16 words: w[t][j] = {reg2j, reg2j+1} ---
        unsigned w0[8], w1[8];
        #pragma unroll
        for (int j = 0; j < 8; ++j) {
            w0[j] = cvt_pk_bf16(sT0[2 * j], sT0[2 * j + 1]);
            w1[j] = cvt_pk_bf16(sT1[2 * j], sT1[2 * j + 1]);
        }
        // --- P^T B-fragments via permlane32_swap (one swap fills 2 words) ---
        bf16x8 pf[4];
        #pragma unroll
        for (int ks = 0; ks < 4; ++ks) {
            const int jb = 4 * (ks & 1);
            unsigned a0 = (ks >> 1) ? w1[jb]     : w0[jb];
            unsigned b0 = (ks >> 1) ? w1[jb + 2] : w0[jb + 2];
            unsigned a1 = (ks >> 1) ? w1[jb + 1] : w0[jb + 1];
            unsigned b1 = (ks >> 1) ? w1[jb + 3] : w0[jb + 3];
            permlane32_swap(a0, b0);
            permlane32_swap(a1, b1);
            union { bf16x8 f; unsigned w[4]; } u;
            u.w[0] = a0; u.w[1] = a1; u.w[2] = b0; u.w[3] = b1;
            pf[ks] = u.f;
        }

        // --- PV: O^T += V^T x P^T ; V^T A-frags via tr-reads ---
        #pragma unroll
        for (int dt = 0; dt < 2; ++dt) {
            s16x4 t[8];
            #pragma unroll
            for (int ks = 0; ks < 4; ++ks) {
                unsigned a = vb + ks * 2048 + hi_ * 1024 + dt * 256 + g16 * 128 + l16 * 8;
                t[ks * 2]     = ds_tr16(a);
                t[ks * 2 + 1] = ds_tr16(a + 512);
            }
            asm volatile("s_waitcnt lgkmcnt(0)" ::: "memory");
            __builtin_amdgcn_sched_barrier(0);
            #pragma unroll
            for (int ks = 0; ks < 4; ++ks) {
                union { bf16x8 f; s16x4 h[2]; } u;
                u.h[0] = t[ks * 2]; u.h[1] = t[ks * 2 + 1];
                if (dt == 0) o0 = __builtin_amdgcn_mfma_f32_32x32x16_bf16(u.f, pf[ks], o0, 0, 0, 0);
                else         o1 = __builtin_amdgcn_mfma_f32_32x32x16_bf16(u.f, pf[ks], o1, 0, 0, 0);
            }
        }
    }

    // --- epilogue: normalize, transpose through LDS, coalesced store ---
    const float inv = 1.f / lsum;
    __syncthreads();
    #pragma unroll
    for (int r = 0; r < 16; ++r) {
        const int d0 = (r & 3) + 8 * (r >> 2) + 4 * hi_;
        Os[wv * 32 + l31][d0]      = f2bf(o0[r] * inv);
        Os[wv * 32 + l31][32 + d0] = f2bf(o1[r] * inv);
    }
    __syncthreads();
    {
        const int row = tid >> 1, c0 = (tid & 1) * 32;
        bf16* op = attn_out + (size_t)(b * NSEQ + q0 + row) * DM + h * 64 + c0;
        #pragma unroll
        for (int e = 0; e < 4; ++e)
            *(bf16x8*)(op + e * 8) = *(const bf16x8*)&Os[row][c0 + e * 8];
    }
}

extern "C" void kernel_launch(void* const* d_in, const int* in_sizes, int n_in,
                              void* d_out, int out_size, void* d_ws, size_t ws_size,
                              hipStream_t stream) {
    const float* x     = (const float*)d_in[0];   // [4,2048,1024] fp32
    const float* w_qkv = (const float*)d_in[1];   // [1024,3072]  fp32
    const float* w_out = (const float*)d_in[2];   // [1024,1024]  fp32
    float* out = (float*)d_out;                   // [4,2048,1024] fp32
    bf16* qkv  = (bf16*)d_ws;                     // [8192,3072] bf16
    bf16* attn = qkv + (size_t)8192 * 3072;       // [8192,1024] bf16

    gemm_t<float, float, bf16><<<dim3(3072/128, 8192/128), 256, 0, stream>>>(x, w_qkv, qkv, 8192, 3072, 1024);
    attn_mfma32<<<dim3(2048/128, 64), 256, 0, stream>>>(qkv, attn);
    gemm_t<bf16, float, float><<<dim3(1024/128, 8192/128), 256, 0, stream>>>(attn, w_out, out, 8192, 1024, 1024);
}

// Round 5
// 289.436 us; speedup vs baseline: 10.6715x; 1.1046x over previous
//
#include <hip/hip_runtime.h>
#include <hip/hip_bf16.h>

typedef __bf16 bf16;
typedef __bf16 bf16x8 __attribute__((ext_vector_type(8)));
typedef float f32x4 __attribute__((ext_vector_type(4)));
typedef float f32x16 __attribute__((ext_vector_type(16)));
typedef short s16x4 __attribute__((ext_vector_type(4)));

#define GLDS16(gp, lp) __builtin_amdgcn_global_load_lds( \
    (const __attribute__((address_space(1))) void*)(gp), \
    (__attribute__((address_space(3))) void*)(lp), 16, 0, 0)

__device__ __forceinline__ bf16 f2bf(float f) {
    unsigned u = __builtin_bit_cast(unsigned, f);
    u = (u + 0x7FFFu + ((u >> 16) & 1u)) >> 16;
    unsigned short s = (unsigned short)u;
    return __builtin_bit_cast(bf16, s);
}
__device__ __forceinline__ void store_c(float* p, float v) { *p = v; }
__device__ __forceinline__ void store_c(bf16*  p, float v) { *p = f2bf(v); }

__device__ __forceinline__ unsigned cvt_pk_bf16(float lo, float hi) {
    unsigned r;
    asm("v_cvt_pk_bf16_f32 %0, %1, %2" : "=v"(r) : "v"(lo), "v"(hi));
    return r;
}
__device__ __forceinline__ void permlane32_swap(unsigned &a, unsigned &b) {
    asm("v_permlane32_swap_b32 %0, %1" : "+v"(a), "+v"(b));
}
// LDS transpose read from a [4][16]-subtiled bf16 region: lane gets col (lane&15),
// elems j = rows 0..3 of the subtile addressed by (addr - (lane&15)*8).
__device__ __forceinline__ s16x4 ds_tr16(unsigned addr) {
    s16x4 d;
    asm volatile("ds_read_b64_tr_b16 %0, %1" : "=v"(d) : "v"(addr));
    return d;
}

// ---- fp32 -> bf16 bulk convert (n8 = nelems/8) ----
__global__ __launch_bounds__(256) void cvt_f32_bf16(
    const float* __restrict__ in, bf16* __restrict__ out, int n8)
{
    int i = blockIdx.x * 256 + threadIdx.x;
    if (i >= n8) return;
    f32x4 a = *(const f32x4*)(in + (size_t)i * 8);
    f32x4 b = *(const f32x4*)(in + (size_t)i * 8 + 4);
    bf16x8 o;
    #pragma unroll
    for (int j = 0; j < 4; ++j) { o[j] = f2bf(a[j]); o[4 + j] = f2bf(b[j]); }
    *(bf16x8*)(out + (size_t)i * 8) = o;
}

// ---------------------------------------------------------------------------
// m97-style GEMM: C[M,N] = A[M,K]·B[K,N]. 128x128 tile, BK=32, 4 waves,
// single-buffer LDS, 2 barriers/K-step.
//  A: bf16 row-major, staged via global_load_lds width=16 (lane-linear LDS).
//  B: staged into subtiled LDS [8 kq][8 nb][4][16]; fragments via ds_read_b64_tr_b16.
//    BMODE 0: B fp32 row-major -> reg-stage + cvt + lane-linear b128 writes.
//    BMODE 1: B bf16 row-major -> global_load_lds with pre-swizzled per-lane source.
// ---------------------------------------------------------------------------
template <int BMODE, typename TC>
__global__ __launch_bounds__(256) void gemm_glds(
    const bf16* __restrict__ A, const void* __restrict__ Bv, TC* __restrict__ C,
    int M, int N, int K)
{
    __shared__ alignas(16) bf16 As[128 * 32];   // [row][k] row-major, 8 KB
    __shared__ alignas(16) bf16 Bs[32 * 128];   // subtiled [kq][nb][4][16], 8 KB

    const int tid  = threadIdx.x;
    const int wv   = tid >> 6;
    const int lane = tid & 63;
    const int lr   = lane & 15;
    const int kb   = lane >> 4;
    const int wr   = wv >> 1, wc = wv & 1;
    const int brow = blockIdx.y * 128;
    const int bcol = blockIdx.x * 128;

    f32x4 acc[4][4] = {};

    // A staging: issue t: LDS bytes L = t*4096 + wv*1024 + lane*16
    //  -> row = t*64 + wv*16 + lane/4, col elems = (lane&3)*8
    const int ar0 = wv * 16 + (lane >> 2);
    const int ac0 = (lane & 3) * 8;

    // B BMODE1 glds source: same linear L over Bs: s = L/128 (subtile), r, c0
    const int bL   = wv * 1024 + lane * 16;
    const int bs0  = bL >> 7;                 // subtile idx for t=0 (t=1: +32)
    const int b_r  = (bL & 127) >> 5;
    const int b_c0 = (bL & 31) >> 1;

    // B BMODE0: thread owns Bs elems [tid*16, +16) = subtile tid>>2, row tid&3
    const int b0_k = ((tid >> 5) << 2) + (tid & 3);
    const int b0_n = ((tid >> 2) & 7) * 16;

    const float* Bf = (const float*)Bv;
    const bf16*  Bh = (const bf16*)Bv;

    for (int k0 = 0; k0 < K; k0 += 32) {
        f32x4 breg[4];
        if (BMODE == 0) {
            const float* bp = Bf + (size_t)(k0 + b0_k) * N + bcol + b0_n;
            #pragma unroll
            for (int e = 0; e < 4; ++e) breg[e] = *(const f32x4*)(bp + e * 4);
        }
        __syncthreads();   // previous tile fully consumed
        #pragma unroll
        for (int t = 0; t < 2; ++t)
            GLDS16(A + (size_t)(brow + t * 64 + ar0) * K + k0 + ac0,
                   &As[t * 2048 + wv * 512]);
        if (BMODE == 1) {
            #pragma unroll
            for (int t = 0; t < 2; ++t) {
                int s = bs0 + t * 32;
                GLDS16(Bh + (size_t)(k0 + (s >> 3) * 4 + b_r) * N + bcol + (s & 7) * 16 + b_c0,
                       &Bs[t * 2048 + wv * 512]);
            }
        } else {
            alignas(16) bf16 bb[16];
            #pragma unroll
            for (int e = 0; e < 4; ++e)
                #pragma unroll
                for (int j = 0; j < 4; ++j) bb[e * 4 + j] = f2bf(breg[e][j]);
            *(bf16x8*)&Bs[tid * 16]     = *(bf16x8*)bb;
            *(bf16x8*)&Bs[tid * 16 + 8] = *(bf16x8*)(bb + 8);
        }
        __syncthreads();   // compiler drains vmcnt/lgkmcnt here

        bf16x8 af[4], bfr[4];
        #pragma unroll
        for (int m = 0; m < 4; ++m)
            af[m] = *(const bf16x8*)&As[(wr * 64 + m * 16 + lr) * 32 + kb * 8];
        {
            s16x4 tr[8];
            const unsigned bsb = (unsigned)(uintptr_t)Bs + kb * 2048 + lr * 8;
            #pragma unroll
            for (int nt = 0; nt < 4; ++nt) {
                unsigned a = bsb + (wc * 4 + nt) * 128;
                tr[nt * 2]     = ds_tr16(a);          // k = kb*8 + 0..3
                tr[nt * 2 + 1] = ds_tr16(a + 1024);   // k = kb*8 + 4..7
            }
            asm volatile("s_waitcnt lgkmcnt(0)" ::: "memory");
            __builtin_amdgcn_sched_barrier(0);
            #pragma unroll
            for (int nt = 0; nt < 4; ++nt) {
                union { bf16x8 f; s16x4 h[2]; } u;
                u.h[0] = tr[nt * 2]; u.h[1] = tr[nt * 2 + 1];
                bfr[nt] = u.f;
            }
        }
        #pragma unroll
        for (int m = 0; m < 4; ++m)
            #pragma unroll
            for (int n = 0; n < 4; ++n)
                acc[m][n] = __builtin_amdgcn_mfma_f32_16x16x32_bf16(af[m], bfr[n], acc[m][n], 0, 0, 0);
    }

    #pragma unroll
    for (int m = 0; m < 4; ++m)
        #pragma unroll
        for (int n = 0; n < 4; ++n)
            #pragma unroll
            for (int r = 0; r < 4; ++r) {
                int row = brow + wr * 64 + m * 16 + kb * 4 + r;   // verified C-layout
                int col = bcol + wc * 64 + n * 16 + lr;
                store_c(&C[(size_t)row * N + col], acc[m][n][r]);
            }
}

// ---------------------------------------------------------------------------
// MFMA-32x32 flash attention, swapped-operand structure (unchanged from R3).
// ---------------------------------------------------------------------------
__global__ __launch_bounds__(256) void attn_mfma32(
    const bf16* __restrict__ qkv, bf16* __restrict__ attn_out)
{
    constexpr int NSEQ = 2048, DM = 1024, LD = 3072, KVB = 64, QB = 128;
    __shared__ alignas(16) char smem[18432];
    bf16 (*Ks)[72] = (bf16 (*)[72])smem;      // [64 kv][72] row-major K
    bf16 *Vs       = (bf16*)(smem + 9216);    // [16 kq][4 cb][4][16] subtiled V
    bf16 (*Os)[72] = (bf16 (*)[72])smem;      // epilogue overlay

    const int tid = threadIdx.x;
    const int wv = tid >> 6, lane = tid & 63;
    const int l31 = lane & 31;
    const int hi_ = lane >> 5;
    const int g16 = (lane >> 4) & 1;
    const int l16 = lane & 15;
    const int q0 = blockIdx.x * QB;
    const int bh = blockIdx.y;
    const int b = bh >> 4, h = bh & 15;

    const bf16* qbase = qkv + (size_t)(b * NSEQ) * LD + h * 64;
    const bf16* kbase = qbase + DM;
    const bf16* vbase = qbase + 2 * DM;

    bf16x8 qf[4];
    {
        const bf16* qp = qbase + (size_t)(q0 + wv * 32 + l31) * LD + hi_ * 8;
        #pragma unroll
        for (int ds = 0; ds < 4; ++ds) {
            bf16x8 t = *(const bf16x8*)(qp + ds * 16);
            #pragma unroll
            for (int e = 0; e < 8; ++e) t[e] = f2bf((float)t[e] * 0.125f);
            qf[ds] = t;
        }
    }

    f32x16 o0 = {}, o1 = {};
    float mrow = -INFINITY, lsum = 0.f;

    const int krow = tid >> 2, kcol = (tid & 3) * 16;
    const unsigned vb = (unsigned)(uintptr_t)Vs;

    for (int kt = 0; kt < NSEQ / KVB; ++kt) {
        const int j0 = kt * KVB;
        bf16x8 kr0 = *(const bf16x8*)(kbase + (size_t)(j0 + krow) * LD + kcol);
        bf16x8 kr1 = *(const bf16x8*)(kbase + (size_t)(j0 + krow) * LD + kcol + 8);
        bf16x8 vr[2];
        #pragma unroll
        for (int w = 0; w < 2; ++w) {
            int L = w * 2048 + tid * 8;
            int kq = L >> 8, cb = (L >> 6) & 3, rr = (L >> 4) & 3, c0 = L & 15;
            vr[w] = *(const bf16x8*)(vbase + (size_t)(j0 + kq * 4 + rr) * LD + cb * 16 + c0);
        }
        __syncthreads();
        *(bf16x8*)&Ks[krow][kcol]       = kr0;
        *(bf16x8*)&Ks[krow][kcol + 8]   = kr1;
        *(bf16x8*)(Vs + tid * 8)        = vr[0];
        *(bf16x8*)(Vs + 2048 + tid * 8) = vr[1];
        __syncthreads();

        f32x16 sT0 = {}, sT1 = {};
        #pragma unroll
        for (int ds = 0; ds < 4; ++ds) {
            bf16x8 kf = *(const bf16x8*)&Ks[l31][ds * 16 + hi_ * 8];
            sT0 = __builtin_amdgcn_mfma_f32_32x32x16_bf16(kf, qf[ds], sT0, 0, 0, 0);
        }
        #pragma unroll
        for (int ds = 0; ds < 4; ++ds) {
            bf16x8 kf = *(const bf16x8*)&Ks[32 + l31][ds * 16 + hi_ * 8];
            sT1 = __builtin_amdgcn_mfma_f32_32x32x16_bf16(kf, qf[ds], sT1, 0, 0, 0);
        }

        float pm = sT0[0];
        #pragma unroll
        for (int r = 1; r < 16; ++r) pm = fmaxf(pm, sT0[r]);
        #pragma unroll
        for (int r = 0; r < 16; ++r) pm = fmaxf(pm, sT1[r]);
        pm = fmaxf(pm, __shfl_xor(pm, 32));
        const float mn = fmaxf(mrow, pm);
        const float corr = __expf(mrow - mn);
        mrow = mn;
        float ps = 0.f;
        #pragma unroll
        for (int r = 0; r < 16; ++r) { sT0[r] = __expf(sT0[r] - mn); ps += sT0[r]; }
        #pragma unroll
        for (int r = 0; r < 16; ++r) { sT1[r] = __expf(sT1[r] - mn); ps += sT1[r]; }
        ps += __shfl_xor(ps, 32);
        lsum = lsum * corr + ps;
        #pragma unroll
        for (int r = 0; r < 16; ++r) { o0[r] *= corr; o1[r] *= corr; }

        unsigned w0[8], w1[8];
        #pragma unroll
        for (int j = 0; j < 8; ++j) {
            w0[j] = cvt_pk_bf16(sT0[2 * j], sT0[2 * j + 1]);
            w1[j] = cvt_pk_bf16(sT1[2 * j], sT1[2 * j + 1]);
        }
        bf16x8 pf[4];
        #pragma unroll
        for (int ks = 0; ks < 4; ++ks) {
            const int jb = 4 * (ks & 1);
            unsigned a0 = (ks >> 1) ? w1[jb]     : w0[jb];
            unsigned b0 = (ks >> 1) ? w1[jb + 2] : w0[jb + 2];
            unsigned a1 = (ks >> 1) ? w1[jb + 1] : w0[jb + 1];
            unsigned b1 = (ks >> 1) ? w1[jb + 3] : w0[jb + 3];
            permlane32_swap(a0, b0);
            permlane32_swap(a1, b1);
            union { bf16x8 f; unsigned w[4]; } u;
            u.w[0] = a0; u.w[1] = a1; u.w[2] = b0; u.w[3] = b1;
            pf[ks] = u.f;
        }

        #pragma unroll
        for (int dt = 0; dt < 2; ++dt) {
            s16x4 t[8];
            #pragma unroll
            for (int ks = 0; ks < 4; ++ks) {
                unsigned a = vb + ks * 2048 + hi_ * 1024 + dt * 256 + g16 * 128 + l16 * 8;
                t[ks * 2]     = ds_tr16(a);
                t[ks * 2 + 1] = ds_tr16(a + 512);
            }
            asm volatile("s_waitcnt lgkmcnt(0)" ::: "memory");
            __builtin_amdgcn_sched_barrier(0);
            #pragma unroll
            for (int ks = 0; ks < 4; ++ks) {
                union { bf16x8 f; s16x4 h[2]; } u;
                u.h[0] = t[ks * 2]; u.h[1] = t[ks * 2 + 1];
                if (dt == 0) o0 = __builtin_amdgcn_mfma_f32_32x32x16_bf16(u.f, pf[ks], o0, 0, 0, 0);
                else         o1 = __builtin_amdgcn_mfma_f32_32x32x16_bf16(u.f, pf[ks], o1, 0, 0, 0);
            }
        }
    }

    const float inv = 1.f / lsum;
    __syncthreads();
    #pragma unroll
    for (int r = 0; r < 16; ++r) {
        const int d0 = (r & 3) + 8 * (r >> 2) + 4 * hi_;
        Os[wv * 32 + l31][d0]      = f2bf(o0[r] * inv);
        Os[wv * 32 + l31][32 + d0] = f2bf(o1[r] * inv);
    }
    __syncthreads();
    {
        const int row = tid >> 1, c0 = (tid & 1) * 32;
        bf16* op = attn_out + (size_t)(b * NSEQ + q0 + row) * DM + h * 64 + c0;
        #pragma unroll
        for (int e = 0; e < 4; ++e)
            *(bf16x8*)(op + e * 8) = *(const bf16x8*)&Os[row][c0 + e * 8];
    }
}

extern "C" void kernel_launch(void* const* d_in, const int* in_sizes, int n_in,
                              void* d_out, int out_size, void* d_ws, size_t ws_size,
                              hipStream_t stream) {
    const float* x     = (const float*)d_in[0];   // [4,2048,1024] fp32
    const float* w_qkv = (const float*)d_in[1];   // [1024,3072]  fp32
    const float* w_out = (const float*)d_in[2];   // [1024,1024]  fp32
    float* out = (float*)d_out;                   // [4,2048,1024] fp32

    // ws layout (64 MiB total, matches proven footprint):
    //   [0, 48 MiB)   qkv (gemm1 out) ... later reused for w_out_bf16
    //   [48, 64 MiB)  x_bf16 (gemm1 A) ... later reused for attn output
    bf16* qkv   = (bf16*)d_ws;
    bf16* x_bf  = qkv + (size_t)8192 * 3072;
    bf16* attnb = x_bf;                  // after gemm1, x_bf is dead
    bf16* wo_bf = (bf16*)d_ws;           // after attn, qkv is dead

    cvt_f32_bf16<<<4096, 256, 0, stream>>>(x, x_bf, 8192 * 1024 / 8);
    gemm_glds<0, bf16><<<dim3(3072 / 128, 8192 / 128), 256, 0, stream>>>(
        x_bf, (const void*)w_qkv, qkv, 8192, 3072, 1024);
    attn_mfma32<<<dim3(2048 / 128, 64), 256, 0, stream>>>(qkv, attnb);
    cvt_f32_bf16<<<512, 256, 0, stream>>>(w_out, wo_bf, 1024 * 1024 / 8);
    gemm_glds<1, float><<<dim3(1024 / 128, 8192 / 128), 256, 0, stream>>>(
        attnb, (const void*)wo_bf, out, 8192, 1024, 1024);
}

// Round 6
// 240.512 us; speedup vs baseline: 12.8423x; 1.2034x over previous
//
#include <hip/hip_runtime.h>
#include <hip/hip_bf16.h>

typedef __bf16 bf16;
typedef __bf16 bf16x8 __attribute__((ext_vector_type(8)));
typedef float f32x4 __attribute__((ext_vector_type(4)));
typedef float f32x16 __attribute__((ext_vector_type(16)));
typedef short s16x4 __attribute__((ext_vector_type(4)));

#define GLDS16(gp, lp) __builtin_amdgcn_global_load_lds( \
    (const __attribute__((address_space(1))) void*)(gp), \
    (__attribute__((address_space(3))) void*)(lp), 16, 0, 0)

__device__ __forceinline__ bf16 f2bf(float f) {
    unsigned u = __builtin_bit_cast(unsigned, f);
    u = (u + 0x7FFFu + ((u >> 16) & 1u)) >> 16;
    unsigned short s = (unsigned short)u;
    return __builtin_bit_cast(bf16, s);
}
__device__ __forceinline__ void store_c(float* p, float v) { *p = v; }
__device__ __forceinline__ void store_c(bf16*  p, float v) { *p = f2bf(v); }

__device__ __forceinline__ unsigned cvt_pk_bf16(float lo, float hi) {
    unsigned r;
    asm("v_cvt_pk_bf16_f32 %0, %1, %2" : "=v"(r) : "v"(lo), "v"(hi));
    return r;
}
__device__ __forceinline__ void permlane32_swap(unsigned &a, unsigned &b) {
    asm("v_permlane32_swap_b32 %0, %1" : "+v"(a), "+v"(b));
}
// LDS transpose read from a [4][16]-subtiled bf16 region.
__device__ __forceinline__ s16x4 ds_tr16(unsigned addr) {
    s16x4 d;
    asm volatile("ds_read_b64_tr_b16 %0, %1" : "=v"(d) : "v"(addr));
    return d;
}

// ---- fp32 -> bf16 bulk convert (n8 = nelems/8) ----
__global__ __launch_bounds__(256) void cvt_f32_bf16(
    const float* __restrict__ in, bf16* __restrict__ out, int n8)
{
    int i = blockIdx.x * 256 + threadIdx.x;
    if (i >= n8) return;
    f32x4 a = *(const f32x4*)(in + (size_t)i * 8);
    f32x4 b = *(const f32x4*)(in + (size_t)i * 8 + 4);
    bf16x8 o;
    #pragma unroll
    for (int j = 0; j < 4; ++j) { o[j] = f2bf(a[j]); o[4 + j] = f2bf(b[j]); }
    *(bf16x8*)(out + (size_t)i * 8) = o;
}

// ---------------------------------------------------------------------------
// m97-style GEMM, all-bf16: C[M,N] = A[M,K]·B[K,N]. 128x128 tile, BK=32,
// 4 waves, single-buffer LDS, 2 barriers/K-step, full global_load_lds staging.
//  A: row-major, lane-linear LDS [row][k].
//  B: subtiled LDS [8 kq][8 nb][4][16] via pre-swizzled per-lane glds source;
//     fragments read with ds_read_b64_tr_b16 (HW transpose).
// ---------------------------------------------------------------------------
template <typename TC>
__global__ __launch_bounds__(256) void gemm_glds(
    const bf16* __restrict__ A, const bf16* __restrict__ B, TC* __restrict__ C,
    int M, int N, int K)
{
    __shared__ alignas(16) bf16 As[128 * 32];   // 8 KB
    __shared__ alignas(16) bf16 Bs[32 * 128];   // 8 KB

    const int tid  = threadIdx.x;
    const int wv   = tid >> 6;
    const int lane = tid & 63;
    const int lr   = lane & 15;
    const int kb   = lane >> 4;
    const int wr   = wv >> 1, wc = wv & 1;
    const int brow = blockIdx.y * 128;
    const int bcol = blockIdx.x * 128;

    f32x4 acc[4][4] = {};

    // A staging: LDS byte L = t*4096 + wv*1024 + lane*16 -> row t*64+wv*16+lane/4
    const int ar0 = wv * 16 + (lane >> 2);
    const int ac0 = (lane & 3) * 8;

    // B staging: same linear L over subtiled Bs: s = byteL/128, r=(byteL&127)>>5,
    // c0=(byteL&31)/2; global src row = k0 + (s>>3)*4 + r, col = bcol + (s&7)*16 + c0
    const int bL   = wv * 1024 + lane * 16;
    const int bs0  = bL >> 7;
    const int b_r  = (bL & 127) >> 5;
    const int b_c0 = (bL & 31) >> 1;

    for (int k0 = 0; k0 < K; k0 += 32) {
        __syncthreads();   // previous tile fully consumed
        #pragma unroll
        for (int t = 0; t < 2; ++t)
            GLDS16(A + (size_t)(brow + t * 64 + ar0) * K + k0 + ac0,
                   &As[t * 2048 + wv * 512]);
        #pragma unroll
        for (int t = 0; t < 2; ++t) {
            int s = bs0 + t * 32;
            GLDS16(B + (size_t)(k0 + (s >> 3) * 4 + b_r) * N + bcol + (s & 7) * 16 + b_c0,
                   &Bs[t * 2048 + wv * 512]);
        }
        __syncthreads();   // compiler drains vmcnt here

        bf16x8 af[4], bfr[4];
        #pragma unroll
        for (int m = 0; m < 4; ++m)
            af[m] = *(const bf16x8*)&As[(wr * 64 + m * 16 + lr) * 32 + kb * 8];
        {
            s16x4 tr[8];
            const unsigned bsb = (unsigned)(uintptr_t)Bs + kb * 2048 + lr * 8;
            #pragma unroll
            for (int nt = 0; nt < 4; ++nt) {
                unsigned a = bsb + (wc * 4 + nt) * 128;
                tr[nt * 2]     = ds_tr16(a);          // k = kb*8 + 0..3
                tr[nt * 2 + 1] = ds_tr16(a + 1024);   // k = kb*8 + 4..7
            }
            asm volatile("s_waitcnt lgkmcnt(0)" ::: "memory");
            __builtin_amdgcn_sched_barrier(0);
            #pragma unroll
            for (int nt = 0; nt < 4; ++nt) {
                union { bf16x8 f; s16x4 h[2]; } u;
                u.h[0] = tr[nt * 2]; u.h[1] = tr[nt * 2 + 1];
                bfr[nt] = u.f;
            }
        }
        #pragma unroll
        for (int m = 0; m < 4; ++m)
            #pragma unroll
            for (int n = 0; n < 4; ++n)
                acc[m][n] = __builtin_amdgcn_mfma_f32_16x16x32_bf16(af[m], bfr[n], acc[m][n], 0, 0, 0);
    }

    #pragma unroll
    for (int m = 0; m < 4; ++m)
        #pragma unroll
        for (int n = 0; n < 4; ++n)
            #pragma unroll
            for (int r = 0; r < 4; ++r) {
                int row = brow + wr * 64 + m * 16 + kb * 4 + r;   // verified C-layout
                int col = bcol + wc * 64 + n * 16 + lr;
                store_c(&C[(size_t)row * N + col], acc[m][n][r]);
            }
}

// ---------------------------------------------------------------------------
// MFMA-32x32 flash attention, swapped-operand structure (unchanged).
// ---------------------------------------------------------------------------
__global__ __launch_bounds__(256) void attn_mfma32(
    const bf16* __restrict__ qkv, bf16* __restrict__ attn_out)
{
    constexpr int NSEQ = 2048, DM = 1024, LD = 3072, KVB = 64, QB = 128;
    __shared__ alignas(16) char smem[18432];
    bf16 (*Ks)[72] = (bf16 (*)[72])smem;      // [64 kv][72] row-major K
    bf16 *Vs       = (bf16*)(smem + 9216);    // [16 kq][4 cb][4][16] subtiled V
    bf16 (*Os)[72] = (bf16 (*)[72])smem;      // epilogue overlay

    const int tid = threadIdx.x;
    const int wv = tid >> 6, lane = tid & 63;
    const int l31 = lane & 31;
    const int hi_ = lane >> 5;
    const int g16 = (lane >> 4) & 1;
    const int l16 = lane & 15;
    const int q0 = blockIdx.x * QB;
    const int bh = blockIdx.y;
    const int b = bh >> 4, h = bh & 15;

    const bf16* qbase = qkv + (size_t)(b * NSEQ) * LD + h * 64;
    const bf16* kbase = qbase + DM;
    const bf16* vbase = qbase + 2 * DM;

    bf16x8 qf[4];
    {
        const bf16* qp = qbase + (size_t)(q0 + wv * 32 + l31) * LD + hi_ * 8;
        #pragma unroll
        for (int ds = 0; ds < 4; ++ds) {
            bf16x8 t = *(const bf16x8*)(qp + ds * 16);
            #pragma unroll
            for (int e = 0; e < 8; ++e) t[e] = f2bf((float)t[e] * 0.125f);
            qf[ds] = t;
        }
    }

    f32x16 o0 = {}, o1 = {};
    float mrow = -INFINITY, lsum = 0.f;

    const int krow = tid >> 2, kcol = (tid & 3) * 16;
    const unsigned vb = (unsigned)(uintptr_t)Vs;

    for (int kt = 0; kt < NSEQ / KVB; ++kt) {
        const int j0 = kt * KVB;
        bf16x8 kr0 = *(const bf16x8*)(kbase + (size_t)(j0 + krow) * LD + kcol);
        bf16x8 kr1 = *(const bf16x8*)(kbase + (size_t)(j0 + krow) * LD + kcol + 8);
        bf16x8 vr[2];
        #pragma unroll
        for (int w = 0; w < 2; ++w) {
            int L = w * 2048 + tid * 8;
            int kq = L >> 8, cb = (L >> 6) & 3, rr = (L >> 4) & 3, c0 = L & 15;
            vr[w] = *(const bf16x8*)(vbase + (size_t)(j0 + kq * 4 + rr) * LD + cb * 16 + c0);
        }
        __syncthreads();
        *(bf16x8*)&Ks[krow][kcol]       = kr0;
        *(bf16x8*)&Ks[krow][kcol + 8]   = kr1;
        *(bf16x8*)(Vs + tid * 8)        = vr[0];
        *(bf16x8*)(Vs + 2048 + tid * 8) = vr[1];
        __syncthreads();

        f32x16 sT0 = {}, sT1 = {};
        #pragma unroll
        for (int ds = 0; ds < 4; ++ds) {
            bf16x8 kf = *(const bf16x8*)&Ks[l31][ds * 16 + hi_ * 8];
            sT0 = __builtin_amdgcn_mfma_f32_32x32x16_bf16(kf, qf[ds], sT0, 0, 0, 0);
        }
        #pragma unroll
        for (int ds = 0; ds < 4; ++ds) {
            bf16x8 kf = *(const bf16x8*)&Ks[32 + l31][ds * 16 + hi_ * 8];
            sT1 = __builtin_amdgcn_mfma_f32_32x32x16_bf16(kf, qf[ds], sT1, 0, 0, 0);
        }

        float pm = sT0[0];
        #pragma unroll
        for (int r = 1; r < 16; ++r) pm = fmaxf(pm, sT0[r]);
        #pragma unroll
        for (int r = 0; r < 16; ++r) pm = fmaxf(pm, sT1[r]);
        pm = fmaxf(pm, __shfl_xor(pm, 32));
        const float mn = fmaxf(mrow, pm);
        const float corr = __expf(mrow - mn);
        mrow = mn;
        float ps = 0.f;
        #pragma unroll
        for (int r = 0; r < 16; ++r) { sT0[r] = __expf(sT0[r] - mn); ps += sT0[r]; }
        #pragma unroll
        for (int r = 0; r < 16; ++r) { sT1[r] = __expf(sT1[r] - mn); ps += sT1[r]; }
        ps += __shfl_xor(ps, 32);
        lsum = lsum * corr + ps;
        #pragma unroll
        for (int r = 0; r < 16; ++r) { o0[r] *= corr; o1[r] *= corr; }

        unsigned w0[8], w1[8];
        #pragma unroll
        for (int j = 0; j < 8; ++j) {
            w0[j] = cvt_pk_bf16(sT0[2 * j], sT0[2 * j + 1]);
            w1[j] = cvt_pk_bf16(sT1[2 * j], sT1[2 * j + 1]);
        }
        bf16x8 pf[4];
        #pragma unroll
        for (int ks = 0; ks < 4; ++ks) {
            const int jb = 4 * (ks & 1);
            unsigned a0 = (ks >> 1) ? w1[jb]     : w0[jb];
            unsigned b0 = (ks >> 1) ? w1[jb + 2] : w0[jb + 2];
            unsigned a1 = (ks >> 1) ? w1[jb + 1] : w0[jb + 1];
            unsigned b1 = (ks >> 1) ? w1[jb + 3] : w0[jb + 3];
            permlane32_swap(a0, b0);
            permlane32_swap(a1, b1);
            union { bf16x8 f; unsigned w[4]; } u;
            u.w[0] = a0; u.w[1] = a1; u.w[2] = b0; u.w[3] = b1;
            pf[ks] = u.f;
        }

        #pragma unroll
        for (int dt = 0; dt < 2; ++dt) {
            s16x4 t[8];
            #pragma unroll
            for (int ks = 0; ks < 4; ++ks) {
                unsigned a = vb + ks * 2048 + hi_ * 1024 + dt * 256 + g16 * 128 + l16 * 8;
                t[ks * 2]     = ds_tr16(a);
                t[ks * 2 + 1] = ds_tr16(a + 512);
            }
            asm volatile("s_waitcnt lgkmcnt(0)" ::: "memory");
            __builtin_amdgcn_sched_barrier(0);
            #pragma unroll
            for (int ks = 0; ks < 4; ++ks) {
                union { bf16x8 f; s16x4 h[2]; } u;
                u.h[0] = t[ks * 2]; u.h[1] = t[ks * 2 + 1];
                if (dt == 0) o0 = __builtin_amdgcn_mfma_f32_32x32x16_bf16(u.f, pf[ks], o0, 0, 0, 0);
                else         o1 = __builtin_amdgcn_mfma_f32_32x32x16_bf16(u.f, pf[ks], o1, 0, 0, 0);
            }
        }
    }

    const float inv = 1.f / lsum;
    __syncthreads();
    #pragma unroll
    for (int r = 0; r < 16; ++r) {
        const int d0 = (r & 3) + 8 * (r >> 2) + 4 * hi_;
        Os[wv * 32 + l31][d0]      = f2bf(o0[r] * inv);
        Os[wv * 32 + l31][32 + d0] = f2bf(o1[r] * inv);
    }
    __syncthreads();
    {
        const int row = tid >> 1, c0 = (tid & 1) * 32;
        bf16* op = attn_out + (size_t)(b * NSEQ + q0 + row) * DM + h * 64 + c0;
        #pragma unroll
        for (int e = 0; e < 4; ++e)
            *(bf16x8*)(op + e * 8) = *(const bf16x8*)&Os[row][c0 + e * 8];
    }
}

extern "C" void kernel_launch(void* const* d_in, const int* in_sizes, int n_in,
                              void* d_out, int out_size, void* d_ws, size_t ws_size,
                              hipStream_t stream) {
    const float* x     = (const float*)d_in[0];   // [4,2048,1024] fp32
    const float* w_qkv = (const float*)d_in[1];   // [1024,3072]  fp32
    const float* w_out = (const float*)d_in[2];   // [1024,1024]  fp32
    float* out = (float*)d_out;                   // [4,2048,1024] fp32 (32 MiB)

    // Buffers:
    //   x_bf   -> d_out used as scratch (16 MiB of its 32 MiB; gemm2 fully
    //             overwrites d_out at the end -> deterministic across replays)
    //   ws[0,48 MiB)  qkv (gemm1 out); reused for wo_bf after attn
    //   ws[48,64 MiB) wqkv_bf during gemm1; reused for attn output after
    bf16* x_bf    = (bf16*)d_out;
    bf16* qkv     = (bf16*)d_ws;
    bf16* wqkv_bf = qkv + (size_t)8192 * 3072;
    bf16* attnb   = wqkv_bf;             // after gemm1, wqkv_bf is dead
    bf16* wo_bf   = (bf16*)d_ws;         // after attn, qkv is dead

    cvt_f32_bf16<<<4096, 256, 0, stream>>>(x, x_bf, 8192 * 1024 / 8);
    cvt_f32_bf16<<<1536, 256, 0, stream>>>(w_qkv, wqkv_bf, 1024 * 3072 / 8);
    gemm_glds<bf16><<<dim3(3072 / 128, 8192 / 128), 256, 0, stream>>>(
        x_bf, wqkv_bf, qkv, 8192, 3072, 1024);
    attn_mfma32<<<dim3(2048 / 128, 64), 256, 0, stream>>>(qkv, attnb);
    cvt_f32_bf16<<<512, 256, 0, stream>>>(w_out, wo_bf, 1024 * 1024 / 8);
    gemm_glds<float><<<dim3(1024 / 128, 8192 / 128), 256, 0, stream>>>(
        attnb, wo_bf, out, 8192, 1024, 1024);
}

// Round 7
// 220.790 us; speedup vs baseline: 13.9894x; 1.0893x over previous
//
#include <hip/hip_runtime.h>
#include <hip/hip_bf16.h>

typedef __bf16 bf16;
typedef __bf16 bf16x8 __attribute__((ext_vector_type(8)));
typedef float f32x4 __attribute__((ext_vector_type(4)));
typedef float f32x16 __attribute__((ext_vector_type(16)));
typedef short s16x4 __attribute__((ext_vector_type(4)));

#define GLDS16(gp, lp) __builtin_amdgcn_global_load_lds( \
    (const __attribute__((address_space(1))) void*)(gp), \
    (__attribute__((address_space(3))) void*)(lp), 16, 0, 0)

__device__ __forceinline__ bf16 f2bf(float f) {
    unsigned u = __builtin_bit_cast(unsigned, f);
    u = (u + 0x7FFFu + ((u >> 16) & 1u)) >> 16;
    unsigned short s = (unsigned short)u;
    return __builtin_bit_cast(bf16, s);
}
__device__ __forceinline__ void store_c(float* p, float v) { *p = v; }
__device__ __forceinline__ void store_c(bf16*  p, float v) { *p = f2bf(v); }

__device__ __forceinline__ float exp2_fast(float x) {   // native v_exp (exp2)
    float r; asm("v_exp_f32 %0, %1" : "=v"(r) : "v"(x)); return r;
}
__device__ __forceinline__ unsigned cvt_pk_bf16(float lo, float hi) {
    unsigned r;
    asm("v_cvt_pk_bf16_f32 %0, %1, %2" : "=v"(r) : "v"(lo), "v"(hi));
    return r;
}
__device__ __forceinline__ void permlane32_swap(unsigned &a, unsigned &b) {
    asm("v_permlane32_swap_b32 %0, %1" : "+v"(a), "+v"(b));
}
// LDS transpose read from a [4][16]-subtiled bf16 region.
__device__ __forceinline__ s16x4 ds_tr16(unsigned addr) {
    s16x4 d;
    asm volatile("ds_read_b64_tr_b16 %0, %1" : "=v"(d) : "v"(addr));
    return d;
}

// ---- fp32 -> bf16 bulk convert (n8 = nelems/8) ----
__global__ __launch_bounds__(256) void cvt_f32_bf16(
    const float* __restrict__ in, bf16* __restrict__ out, int n8)
{
    int i = blockIdx.x * 256 + threadIdx.x;
    if (i >= n8) return;
    f32x4 a = *(const f32x4*)(in + (size_t)i * 8);
    f32x4 b = *(const f32x4*)(in + (size_t)i * 8 + 4);
    bf16x8 o;
    #pragma unroll
    for (int j = 0; j < 4; ++j) { o[j] = f2bf(a[j]); o[4 + j] = f2bf(b[j]); }
    *(bf16x8*)(out + (size_t)i * 8) = o;
}

// ---------------------------------------------------------------------------
// m97-style GEMM, all-bf16 (unchanged from R5).
// ---------------------------------------------------------------------------
template <typename TC>
__global__ __launch_bounds__(256) void gemm_glds(
    const bf16* __restrict__ A, const bf16* __restrict__ B, TC* __restrict__ C,
    int M, int N, int K)
{
    __shared__ alignas(16) bf16 As[128 * 32];
    __shared__ alignas(16) bf16 Bs[32 * 128];

    const int tid  = threadIdx.x;
    const int wv   = tid >> 6;
    const int lane = tid & 63;
    const int lr   = lane & 15;
    const int kb   = lane >> 4;
    const int wr   = wv >> 1, wc = wv & 1;
    const int brow = blockIdx.y * 128;
    const int bcol = blockIdx.x * 128;

    f32x4 acc[4][4] = {};

    const int ar0 = wv * 16 + (lane >> 2);
    const int ac0 = (lane & 3) * 8;

    const int bL   = wv * 1024 + lane * 16;
    const int bs0  = bL >> 7;
    const int b_r  = (bL & 127) >> 5;
    const int b_c0 = (bL & 31) >> 1;

    for (int k0 = 0; k0 < K; k0 += 32) {
        __syncthreads();
        #pragma unroll
        for (int t = 0; t < 2; ++t)
            GLDS16(A + (size_t)(brow + t * 64 + ar0) * K + k0 + ac0,
                   &As[t * 2048 + wv * 512]);
        #pragma unroll
        for (int t = 0; t < 2; ++t) {
            int s = bs0 + t * 32;
            GLDS16(B + (size_t)(k0 + (s >> 3) * 4 + b_r) * N + bcol + (s & 7) * 16 + b_c0,
                   &Bs[t * 2048 + wv * 512]);
        }
        __syncthreads();

        bf16x8 af[4], bfr[4];
        #pragma unroll
        for (int m = 0; m < 4; ++m)
            af[m] = *(const bf16x8*)&As[(wr * 64 + m * 16 + lr) * 32 + kb * 8];
        {
            s16x4 tr[8];
            const unsigned bsb = (unsigned)(uintptr_t)Bs + kb * 2048 + lr * 8;
            #pragma unroll
            for (int nt = 0; nt < 4; ++nt) {
                unsigned a = bsb + (wc * 4 + nt) * 128;
                tr[nt * 2]     = ds_tr16(a);
                tr[nt * 2 + 1] = ds_tr16(a + 1024);
            }
            asm volatile("s_waitcnt lgkmcnt(0)" ::: "memory");
            __builtin_amdgcn_sched_barrier(0);
            #pragma unroll
            for (int nt = 0; nt < 4; ++nt) {
                union { bf16x8 f; s16x4 h[2]; } u;
                u.h[0] = tr[nt * 2]; u.h[1] = tr[nt * 2 + 1];
                bfr[nt] = u.f;
            }
        }
        #pragma unroll
        for (int m = 0; m < 4; ++m)
            #pragma unroll
            for (int n = 0; n < 4; ++n)
                acc[m][n] = __builtin_amdgcn_mfma_f32_16x16x32_bf16(af[m], bfr[n], acc[m][n], 0, 0, 0);
    }

    #pragma unroll
    for (int m = 0; m < 4; ++m)
        #pragma unroll
        for (int n = 0; n < 4; ++n)
            #pragma unroll
            for (int r = 0; r < 4; ++r) {
                int row = brow + wr * 64 + m * 16 + kb * 4 + r;
                int col = bcol + wc * 64 + n * 16 + lr;
                store_c(&C[(size_t)row * N + col], acc[m][n][r]);
            }
}

// ---------------------------------------------------------------------------
// MFMA-32x32 flash attention, swapped-operand structure.
// R6 changes: exp2-domain scores (Q pre-scaled by 0.125*log2e, raw v_exp),
// defer-max (skip O/l rescale when __all within THR), async-STAGE split
// (next tile's global loads issued before compute), setprio around MFMA.
// ---------------------------------------------------------------------------
__global__ __launch_bounds__(256) void attn_mfma32(
    const bf16* __restrict__ qkv, bf16* __restrict__ attn_out)
{
    constexpr int NSEQ = 2048, DM = 1024, LD = 3072, KVB = 64, QB = 128;
    constexpr int NT = NSEQ / KVB;
    constexpr float THR = 11.5f;               // log2-domain defer threshold
    __shared__ alignas(16) char smem[18432];
    bf16 (*Ks)[72] = (bf16 (*)[72])smem;       // [64 kv][72] row-major K
    bf16 *Vs       = (bf16*)(smem + 9216);     // [16 kq][4 cb][4][16] subtiled V
    bf16 (*Os)[72] = (bf16 (*)[72])smem;       // epilogue overlay

    const int tid = threadIdx.x;
    const int wv = tid >> 6, lane = tid & 63;
    const int l31 = lane & 31;
    const int hi_ = lane >> 5;
    const int g16 = (lane >> 4) & 1;
    const int l16 = lane & 15;
    const int q0 = blockIdx.x * QB;
    const int bh = blockIdx.y;
    const int b = bh >> 4, h = bh & 15;

    const bf16* qbase = qkv + (size_t)(b * NSEQ) * LD + h * 64;
    const bf16* kbase = qbase + DM;
    const bf16* vbase = qbase + 2 * DM;

    // Q fragments, pre-scaled by 0.125*log2(e) -> scores in log2 domain
    bf16x8 qf[4];
    {
        const float QSC = 0.125f * 1.44269504f;
        const bf16* qp = qbase + (size_t)(q0 + wv * 32 + l31) * LD + hi_ * 8;
        #pragma unroll
        for (int ds = 0; ds < 4; ++ds) {
            bf16x8 t = *(const bf16x8*)(qp + ds * 16);
            #pragma unroll
            for (int e = 0; e < 8; ++e) t[e] = f2bf((float)t[e] * QSC);
            qf[ds] = t;
        }
    }

    f32x16 o0 = {}, o1 = {};
    float mrow = -INFINITY, lsum = 0.f;

    const int krow = tid >> 2, kcol = (tid & 3) * 16;
    const unsigned vb = (unsigned)(uintptr_t)Vs;

    auto vload = [&](int j0, int L) {
        int kq = L >> 8, cb = (L >> 6) & 3, rr = (L >> 4) & 3, c0 = L & 15;
        return *(const bf16x8*)(vbase + (size_t)(j0 + kq * 4 + rr) * LD + cb * 16 + c0);
    };

    // prologue: stage tile 0 into regs
    bf16x8 kr0 = *(const bf16x8*)(kbase + (size_t)krow * LD + kcol);
    bf16x8 kr1 = *(const bf16x8*)(kbase + (size_t)krow * LD + kcol + 8);
    bf16x8 vr0 = vload(0, tid * 8);
    bf16x8 vr1 = vload(0, 2048 + tid * 8);

    for (int kt = 0; kt < NT; ++kt) {
        __syncthreads();                       // prev tile fully consumed
        *(bf16x8*)&Ks[krow][kcol]       = kr0;
        *(bf16x8*)&Ks[krow][kcol + 8]   = kr1;
        *(bf16x8*)(Vs + tid * 8)        = vr0;
        *(bf16x8*)(Vs + 2048 + tid * 8) = vr1;
        __syncthreads();                       // LDS ready

        // async-stage: issue next tile's loads now; latency hides under compute
        {
            const int jn = (kt + 1 < NT ? kt + 1 : kt) * KVB;
            kr0 = *(const bf16x8*)(kbase + (size_t)(jn + krow) * LD + kcol);
            kr1 = *(const bf16x8*)(kbase + (size_t)(jn + krow) * LD + kcol + 8);
            vr0 = vload(jn, tid * 8);
            vr1 = vload(jn, 2048 + tid * 8);
        }

        // --- QK^T swapped (scores already in log2 domain) ---
        f32x16 sT0 = {}, sT1 = {};
        __builtin_amdgcn_s_setprio(1);
        #pragma unroll
        for (int ds = 0; ds < 4; ++ds) {
            bf16x8 kf = *(const bf16x8*)&Ks[l31][ds * 16 + hi_ * 8];
            sT0 = __builtin_amdgcn_mfma_f32_32x32x16_bf16(kf, qf[ds], sT0, 0, 0, 0);
        }
        #pragma unroll
        for (int ds = 0; ds < 4; ++ds) {
            bf16x8 kf = *(const bf16x8*)&Ks[32 + l31][ds * 16 + hi_ * 8];
            sT1 = __builtin_amdgcn_mfma_f32_32x32x16_bf16(kf, qf[ds], sT1, 0, 0, 0);
        }
        __builtin_amdgcn_s_setprio(0);

        // --- online softmax, defer-max ---
        float pm = sT0[0];
        #pragma unroll
        for (int r = 1; r < 16; ++r) pm = fmaxf(pm, sT0[r]);
        #pragma unroll
        for (int r = 0; r < 16; ++r) pm = fmaxf(pm, sT1[r]);
        pm = fmaxf(pm, __shfl_xor(pm, 32));
        if (!__all(pm <= mrow + THR)) {
            const float mn = fmaxf(mrow, pm);
            const float corr = exp2_fast(mrow - mn);
            mrow = mn;
            lsum *= corr;
            #pragma unroll
            for (int r = 0; r < 16; ++r) { o0[r] *= corr; o1[r] *= corr; }
        }
        float ps = 0.f;
        #pragma unroll
        for (int r = 0; r < 16; ++r) { sT0[r] = exp2_fast(sT0[r] - mrow); ps += sT0[r]; }
        #pragma unroll
        for (int r = 0; r < 16; ++r) { sT1[r] = exp2_fast(sT1[r] - mrow); ps += sT1[r]; }
        ps += __shfl_xor(ps, 32);
        lsum += ps;

        // --- pack P to bf16 + P^T fragments via permlane32_swap ---
        unsigned w0[8], w1[8];
        #pragma unroll
        for (int j = 0; j < 8; ++j) {
            w0[j] = cvt_pk_bf16(sT0[2 * j], sT0[2 * j + 1]);
            w1[j] = cvt_pk_bf16(sT1[2 * j], sT1[2 * j + 1]);
        }
        bf16x8 pf[4];
        #pragma unroll
        for (int ks = 0; ks < 4; ++ks) {
            const int jb = 4 * (ks & 1);
            unsigned a0 = (ks >> 1) ? w1[jb]     : w0[jb];
            unsigned b0 = (ks >> 1) ? w1[jb + 2] : w0[jb + 2];
            unsigned a1 = (ks >> 1) ? w1[jb + 1] : w0[jb + 1];
            unsigned b1 = (ks >> 1) ? w1[jb + 3] : w0[jb + 3];
            permlane32_swap(a0, b0);
            permlane32_swap(a1, b1);
            union { bf16x8 f; unsigned w[4]; } u;
            u.w[0] = a0; u.w[1] = a1; u.w[2] = b0; u.w[3] = b1;
            pf[ks] = u.f;
        }

        // --- PV: O^T += V^T x P^T ---
        #pragma unroll
        for (int dt = 0; dt < 2; ++dt) {
            s16x4 t[8];
            #pragma unroll
            for (int ks = 0; ks < 4; ++ks) {
                unsigned a = vb + ks * 2048 + hi_ * 1024 + dt * 256 + g16 * 128 + l16 * 8;
                t[ks * 2]     = ds_tr16(a);
                t[ks * 2 + 1] = ds_tr16(a + 512);
            }
            asm volatile("s_waitcnt lgkmcnt(0)" ::: "memory");
            __builtin_amdgcn_sched_barrier(0);
            __builtin_amdgcn_s_setprio(1);
            #pragma unroll
            for (int ks = 0; ks < 4; ++ks) {
                union { bf16x8 f; s16x4 h[2]; } u;
                u.h[0] = t[ks * 2]; u.h[1] = t[ks * 2 + 1];
                if (dt == 0) o0 = __builtin_amdgcn_mfma_f32_32x32x16_bf16(u.f, pf[ks], o0, 0, 0, 0);
                else         o1 = __builtin_amdgcn_mfma_f32_32x32x16_bf16(u.f, pf[ks], o1, 0, 0, 0);
            }
            __builtin_amdgcn_s_setprio(0);
        }
    }

    const float inv = 1.f / lsum;
    __syncthreads();
    #pragma unroll
    for (int r = 0; r < 16; ++r) {
        const int d0 = (r & 3) + 8 * (r >> 2) + 4 * hi_;
        Os[wv * 32 + l31][d0]      = f2bf(o0[r] * inv);
        Os[wv * 32 + l31][32 + d0] = f2bf(o1[r] * inv);
    }
    __syncthreads();
    {
        const int row = tid >> 1, c0 = (tid & 1) * 32;
        bf16* op = attn_out + (size_t)(b * NSEQ + q0 + row) * DM + h * 64 + c0;
        #pragma unroll
        for (int e = 0; e < 4; ++e)
            *(bf16x8*)(op + e * 8) = *(const bf16x8*)&Os[row][c0 + e * 8];
    }
}

extern "C" void kernel_launch(void* const* d_in, const int* in_sizes, int n_in,
                              void* d_out, int out_size, void* d_ws, size_t ws_size,
                              hipStream_t stream) {
    const float* x     = (const float*)d_in[0];   // [4,2048,1024] fp32
    const float* w_qkv = (const float*)d_in[1];   // [1024,3072]  fp32
    const float* w_out = (const float*)d_in[2];   // [1024,1024]  fp32
    float* out = (float*)d_out;                   // [4,2048,1024] fp32 (32 MiB)

    bf16* x_bf    = (bf16*)d_out;                 // scratch in d_out (overwritten by gemm2)
    bf16* qkv     = (bf16*)d_ws;                  // ws[0,48MiB)
    bf16* wqkv_bf = qkv + (size_t)8192 * 3072;    // ws[48,54MiB)
    bf16* attnb   = wqkv_bf;                      // reuse after gemm1
    bf16* wo_bf   = (bf16*)d_ws;                  // reuse after attn

    cvt_f32_bf16<<<4096, 256, 0, stream>>>(x, x_bf, 8192 * 1024 / 8);
    cvt_f32_bf16<<<1536, 256, 0, stream>>>(w_qkv, wqkv_bf, 1024 * 3072 / 8);
    gemm_glds<bf16><<<dim3(3072 / 128, 8192 / 128), 256, 0, stream>>>(
        x_bf, wqkv_bf, qkv, 8192, 3072, 1024);
    attn_mfma32<<<dim3(2048 / 128, 64), 256, 0, stream>>>(qkv, attnb);
    cvt_f32_bf16<<<512, 256, 0, stream>>>(w_out, wo_bf, 1024 * 1024 / 8);
    gemm_glds<float><<<dim3(1024 / 128, 8192 / 128), 256, 0, stream>>>(
        attnb, wo_bf, out, 8192, 1024, 1024);
}